// Round 8
// baseline (231.935 us; speedup 1.0000x reference)
//
#include <hip/hip_runtime.h>
#include <math.h>

constexpr int B = 4, L = 2048, S = 2048, H = 8, D = 64;
constexpr int U  = 40;
constexpr int NT = 40;
constexpr float SCALE = 0.125f;

// ---------------------------------------------------------------- K1: M scores
__global__ void k_compute_M(const float* __restrict__ q, const float* __restrict__ k,
                            const int* __restrict__ idx, float* __restrict__ M) {
    int tid = threadIdx.x;
    int wid = tid >> 6, lane = tid & 63;
    int b = blockIdx.x & 3;
    int l = (blockIdx.x >> 2) * 4 + wid;
    int h = lane >> 3, dg = lane & 7;

    const float4* qr = (const float4*)(q + ((size_t)(b * L + l) * H + h) * D + dg * 8);
    float4 q0 = qr[0], q1 = qr[1];

    const int* irow = idx + l * U;
    const float* kb = k + (size_t)b * S * H * D + (size_t)h * D + dg * 8;
    float vmax = -INFINITY, vsum = 0.f;
#pragma unroll 4
    for (int u = 0; u < U; u++) {
        int s = irow[u];
        const float4* kr = (const float4*)(kb + (size_t)s * H * D);
        float4 k0 = kr[0], k1 = kr[1];
        float acc = q0.x * k0.x + q0.y * k0.y + q0.z * k0.z + q0.w * k0.w
                  + q1.x * k1.x + q1.y * k1.y + q1.z * k1.z + q1.w * k1.w;
        acc += __shfl_xor(acc, 1);
        acc += __shfl_xor(acc, 2);
        acc += __shfl_xor(acc, 4);
        vmax = fmaxf(vmax, acc);
        vsum += acc;
    }
    if (dg == 0) M[(size_t)(b * H + h) * L + l] = vmax - vsum / (float)S;
}

// ---------------------------------------------------------------- K2: top-40 radix select
__device__ inline unsigned int fkey(float f) {
    unsigned int u = __float_as_uint(f);
    return (u & 0x80000000u) ? ~u : (u | 0x80000000u);
}

__global__ void k_topk(const float* __restrict__ M, int* __restrict__ topidx) {
    int bh = blockIdx.x;
    const float* m = M + (size_t)bh * L;
    int tid = threadIdx.x;

    __shared__ int hist[256];
    __shared__ unsigned int prefix_s;
    __shared__ int c_above_s, nsel_s, ntie_s, r_s;
    __shared__ int tie_i[L];

    unsigned int o[8];
    const float4* mr = (const float4*)(m + tid * 8);
    float4 a0 = mr[0], a1 = mr[1];
    o[0] = fkey(a0.x); o[1] = fkey(a0.y); o[2] = fkey(a0.z); o[3] = fkey(a0.w);
    o[4] = fkey(a1.x); o[5] = fkey(a1.y); o[6] = fkey(a1.z); o[7] = fkey(a1.w);

    if (tid == 0) { prefix_s = 0u; c_above_s = 0; nsel_s = 0; ntie_s = 0; }

    for (int sh = 24; sh >= 0; sh -= 8) {
        hist[tid] = 0;
        __syncthreads();
        unsigned int pfx = prefix_s;
#pragma unroll
        for (int j = 0; j < 8; j++) {
            bool match = (sh == 24) || ((o[j] >> (sh + 8)) == (pfx >> (sh + 8)));
            if (match) atomicAdd(&hist[(o[j] >> sh) & 0xFF], 1);
        }
        __syncthreads();
        if (tid < 64) {
            int4 hv = *(const int4*)&hist[tid * 4];
            int lsum = hv.x + hv.y + hv.z + hv.w;
            int s = lsum;
#pragma unroll
            for (int off = 1; off < 64; off <<= 1) {
                int t = __shfl_down(s, off);
                if (tid + off < 64) s += t;
            }
            int tail = s - lsum;
            int acc = c_above_s;
            int need = NT - acc;
            int t3 = tail + hv.w;
            int t2 = t3 + hv.z;
            int t1 = t2 + hv.y;
            int t0 = t1 + hv.x;
            if (t0 >= need && t1 < need) { prefix_s |= (unsigned)(4 * tid + 0) << sh; c_above_s = acc + t1; }
            else if (t1 >= need && t2 < need) { prefix_s |= (unsigned)(4 * tid + 1) << sh; c_above_s = acc + t2; }
            else if (t2 >= need && t3 < need) { prefix_s |= (unsigned)(4 * tid + 2) << sh; c_above_s = acc + t3; }
            else if (t3 >= need && tail < need) { prefix_s |= (unsigned)(4 * tid + 3) << sh; c_above_s = acc + tail; }
        }
        __syncthreads();
    }

    unsigned int T = prefix_s;

#pragma unroll
    for (int j = 0; j < 8; j++) {
        if (o[j] > T) {
            int slot = atomicAdd(&nsel_s, 1);
            topidx[bh * NT + slot] = tid * 8 + j;
        } else if (o[j] == T) {
            int p = atomicAdd(&ntie_s, 1);
            tie_i[p] = tid * 8 + j;
        }
    }
    __syncthreads();
    if (tid == 0) r_s = NT - nsel_s;
    __syncthreads();
    int r = r_s, ntie = ntie_s;

#pragma unroll
    for (int j = 0; j < 8; j++) {
        if (o[j] == T) {
            int myidx = tid * 8 + j;
            int rank = 0;
            for (int p = 0; p < ntie; p++) rank += (tie_i[p] < myidx) ? 1 : 0;
            if (rank < r) {
                int slot = atomicAdd(&nsel_s, 1);
                topidx[bh * NT + slot] = myidx;
            }
        }
    }
}

// ---------------------------------------------------------------- K3: v mean (2-phase)
__global__ void k_meanv_part(const float* __restrict__ v, float* __restrict__ part) {
    int blk = blockIdx.x;
    int b = blk >> 5, c = blk & 31;
    int col = threadIdx.x;
    const float* p = v + ((size_t)(b * S + c * 64)) * 512 + col;
    float acc = 0.f;
#pragma unroll
    for (int s = 0; s < 64; s++) acc += p[(size_t)s * 512];
    part[(size_t)blk * 512 + col] = acc;
}

__global__ void k_meanv_final(const float* __restrict__ part, float* __restrict__ meanv) {
    int b = blockIdx.x; int col = threadIdx.x;
    float acc = 0.f;
#pragma unroll
    for (int c = 0; c < 32; c++) acc += part[(size_t)(b * 32 + c) * 512 + col];
    meanv[b * 512 + col] = acc * (1.f / (float)S);
}

// ---------------------------------------------------------------- K4: attention partials
// 512 thr = 8 waves. Wave g privately owns rows 5g..5g+5: lane holds CPL cols
// of the score row in regs; max/exp/sum via butterfly (no LDS round-trip, no
// barrier); p_s rows are wave-private so write->PV-read needs no syncthreads.
// Exactly ONE barrier (q staging). PV reads p_s as same-address broadcasts.
template <int NCH_>
__global__ __launch_bounds__(512) void k_attn_part(
        const float* __restrict__ q, const float* __restrict__ k,
        const float* __restrict__ v, const int* __restrict__ topidx,
        float* __restrict__ pctx, float* __restrict__ pm, float* __restrict__ pl) {
    constexpr int CS_ = S / NCH_;
    constexpr int CPL = CS_ / 64;
    int blk = blockIdx.x;
    int bh = blk / NCH_, c = blk % NCH_;
    int b = bh / H, h = bh % H;
    int s0 = c * CS_;
    int tid = threadIdx.x;
    int lane = tid & 63, g = tid >> 6;
    int r0 = g * 5;

    __shared__ float q_s[NT][D];
    __shared__ float p_s[NT][CS_ + 4];

    for (int i = tid; i < NT * D; i += 512) {
        int n = i >> 6, d = i & 63;
        int lsel = topidx[bh * NT + n];
        q_s[n][d] = q[((size_t)(b * L + lsel) * H + h) * D + d];
    }
    __syncthreads();

    // ---- scores: lane owns cols lane*CPL .. lane*CPL+CPL-1
    float sc[5][CPL];
#pragma unroll
    for (int r = 0; r < 5; r++)
#pragma unroll
        for (int j = 0; j < CPL; j++) sc[r][j] = 0.f;

    const float* kp = k + ((size_t)(b * S + s0 + lane * CPL) * H + h) * D;

#pragma unroll
    for (int dc = 0; dc < 64; dc += 16) {
        float4 kf[CPL][4];
#pragma unroll
        for (int j = 0; j < CPL; j++) {
            const float* kc = kp + (size_t)j * H * D + dc;
            kf[j][0] = *(const float4*)(kc);
            kf[j][1] = *(const float4*)(kc + 4);
            kf[j][2] = *(const float4*)(kc + 8);
            kf[j][3] = *(const float4*)(kc + 12);
        }
#pragma unroll
        for (int r = 0; r < 5; r++) {
            const float4* qr = (const float4*)&q_s[r0 + r][dc];
            float4 q0 = qr[0], q1 = qr[1], q2 = qr[2], q3 = qr[3];
#pragma unroll
            for (int j = 0; j < CPL; j++) {
                sc[r][j] += q0.x * kf[j][0].x + q0.y * kf[j][0].y + q0.z * kf[j][0].z + q0.w * kf[j][0].w
                          + q1.x * kf[j][1].x + q1.y * kf[j][1].y + q1.z * kf[j][1].z + q1.w * kf[j][1].w
                          + q2.x * kf[j][2].x + q2.y * kf[j][2].y + q2.z * kf[j][2].z + q2.w * kf[j][2].w
                          + q3.x * kf[j][3].x + q3.y * kf[j][3].y + q3.z * kf[j][3].z + q3.w * kf[j][3].w;
            }
        }
    }

    // ---- per-row stats fully in-wave, exp to p_s (wave-private rows)
#pragma unroll
    for (int r = 0; r < 5; r++) {
        float mx = -INFINITY;
#pragma unroll
        for (int j = 0; j < CPL; j++) { sc[r][j] *= SCALE; mx = fmaxf(mx, sc[r][j]); }
#pragma unroll
        for (int off = 1; off < 64; off <<= 1) mx = fmaxf(mx, __shfl_xor(mx, off));
        float e[CPL]; float sum = 0.f;
#pragma unroll
        for (int j = 0; j < CPL; j++) { e[j] = __expf(sc[r][j] - mx); sum += e[j]; }
#pragma unroll
        for (int off = 1; off < 64; off <<= 1) sum += __shfl_xor(sum, off);
        if (CPL == 2) {
            *(float2*)&p_s[r0 + r][lane * 2] = make_float2(e[0], e[1]);
        } else {
            *(float4*)&p_s[r0 + r][lane * CPL] = make_float4(e[0], e[1], e[2], e[3]);
        }
        if (lane == 0) {
            pm[(bh * NCH_ + c) * NT + r0 + r] = mx;
            pl[(bh * NCH_ + c) * NT + r0 + r] = sum;
        }
    }
    // no __syncthreads: PV reads only this wave's own rows (lgkmcnt ordering)

    // ---- PV: lane = d, rows r0..r0+5
    float acc[5];
#pragma unroll
    for (int r = 0; r < 5; r++) acc[r] = 0.f;
    const float* vb = v + ((size_t)(b * S + s0) * H + h) * D + lane;
    for (int t4 = 0; t4 < CS_; t4 += 4) {
        float vd0 = vb[(size_t)(t4 + 0) * H * D];
        float vd1 = vb[(size_t)(t4 + 1) * H * D];
        float vd2 = vb[(size_t)(t4 + 2) * H * D];
        float vd3 = vb[(size_t)(t4 + 3) * H * D];
#pragma unroll
        for (int r = 0; r < 5; r++) {
            float4 p4 = *(const float4*)&p_s[r0 + r][t4];
            acc[r] += p4.x * vd0 + p4.y * vd1 + p4.z * vd2 + p4.w * vd3;
        }
    }
#pragma unroll
    for (int r = 0; r < 5; r++)
        pctx[((size_t)(bh * NCH_ + c) * NT + r0 + r) * D + lane] = acc[r];
}

// ---------------------------------------------------------------- K5: fill with mean
__global__ void k_fill(const float* __restrict__ meanv, float4* __restrict__ out) {
    int i = blockIdx.x * blockDim.x + threadIdx.x;
    int b = i >> 18;
    int col4 = i & 127;
    out[i] = ((const float4*)meanv)[(b << 7) | col4];
}

// ---------------------------------------------------------------- K6: combine + scatter
template <int NCH_>
__global__ void k_combine(const int* __restrict__ topidx, const float* __restrict__ pctx,
                          const float* __restrict__ pm, const float* __restrict__ pl,
                          float* __restrict__ out) {
    int bh = blockIdx.x; int b = bh / H, h = bh % H;
    int tid = threadIdx.x;
    for (int i = tid; i < NT * D; i += 256) {
        int n = i / D, d = i % D;
        float mg = -INFINITY;
#pragma unroll
        for (int c = 0; c < NCH_; c++) mg = fmaxf(mg, pm[(bh * NCH_ + c) * NT + n]);
        float lsum = 0.f, ctx = 0.f;
#pragma unroll
        for (int c = 0; c < NCH_; c++) {
            float w = __expf(pm[(bh * NCH_ + c) * NT + n] - mg);
            lsum += pl[(bh * NCH_ + c) * NT + n] * w;
            ctx  += pctx[((size_t)(bh * NCH_ + c) * NT + n) * D + d] * w;
        }
        int lsel = topidx[bh * NT + n];
        out[((size_t)(b * L + lsel) * H + h) * D + d] = ctx / lsum;
    }
}

// ---------------------------------------------------------------- launch
extern "C" void kernel_launch(void* const* d_in, const int* in_sizes, int n_in,
                              void* d_out, int out_size, void* d_ws, size_t ws_size,
                              hipStream_t stream) {
    const float* q   = (const float*)d_in[0];
    const float* k   = (const float*)d_in[1];
    const float* v   = (const float*)d_in[2];
    const int*   idx = (const int*)d_in[3];
    float* out = (float*)d_out;

    float* ws = (float*)d_ws;
    float* M      = ws;                         // 65536 floats (reused as meanv partials)
    int*   topidx = (int*)(ws + 65536);         // 1280 ints
    float* meanv  = ws + 65536 + 1280;          // 2048
    float* pm     = meanv + 2048;               // B*H*NCH*NT

    k_compute_M<<<B * L / 4, 256, 0, stream>>>(q, k, idx, M);
    k_topk<<<B * H, 256, 0, stream>>>(M, topidx);
    k_meanv_part<<<B * 32, 512, 0, stream>>>(v, M);
    k_meanv_final<<<B, 512, 0, stream>>>(M, meanv);

    // choose chunk count by available workspace
    constexpr size_t base_floats = 65536 + 1280 + 2048;
    constexpr size_t need16 = (base_floats + 2ull * (32 * 16 * 40) + 32ull * 16 * 40 * 64) * 4;
    if (ws_size >= need16) {
        constexpr int NCH_ = 16;
        float* pl   = pm + 32 * NCH_ * NT;
        float* pctx = pl + 32 * NCH_ * NT;
        k_attn_part<NCH_><<<B * H * NCH_, 512, 0, stream>>>(q, k, v, topidx, pctx, pm, pl);
        k_fill<<<(B * L * H * D / 4) / 256, 256, 0, stream>>>(meanv, (float4*)out);
        k_combine<NCH_><<<B * H, 256, 0, stream>>>(topidx, pctx, pm, pl, out);
    } else {
        constexpr int NCH_ = 8;
        float* pl   = pm + 32 * NCH_ * NT;
        float* pctx = pl + 32 * NCH_ * NT;
        k_attn_part<NCH_><<<B * H * NCH_, 512, 0, stream>>>(q, k, v, topidx, pctx, pm, pl);
        k_fill<<<(B * L * H * D / 4) / 256, 256, 0, stream>>>(meanv, (float4*)out);
        k_combine<NCH_><<<B * H, 256, 0, stream>>>(topidx, pctx, pm, pl, out);
    }
}

// Round 9
// 191.611 us; speedup vs baseline: 1.2104x; 1.2104x over previous
//
#include <hip/hip_runtime.h>
#include <math.h>

constexpr int B = 4, L = 2048, S = 2048, H = 8, D = 64;
constexpr int U  = 40;
constexpr int NT = 40;
constexpr int NCH = 8;
constexpr int CS = S / NCH;          // 256
constexpr int RH = 20;               // rows per attn block (40 split across 2 blocks)
constexpr float SCALE = 0.125f;

// ---------------------------------------------------------------- K1: M scores
__global__ void k_compute_M(const float* __restrict__ q, const float* __restrict__ k,
                            const int* __restrict__ idx, float* __restrict__ M) {
    int tid = threadIdx.x;
    int wid = tid >> 6, lane = tid & 63;
    int b = blockIdx.x & 3;
    int l = (blockIdx.x >> 2) * 4 + wid;
    int h = lane >> 3, dg = lane & 7;

    const float4* qr = (const float4*)(q + ((size_t)(b * L + l) * H + h) * D + dg * 8);
    float4 q0 = qr[0], q1 = qr[1];

    const int* irow = idx + l * U;
    const float* kb = k + (size_t)b * S * H * D + (size_t)h * D + dg * 8;
    float vmax = -INFINITY, vsum = 0.f;
#pragma unroll 4
    for (int u = 0; u < U; u++) {
        int s = irow[u];
        const float4* kr = (const float4*)(kb + (size_t)s * H * D);
        float4 k0 = kr[0], k1 = kr[1];
        float acc = q0.x * k0.x + q0.y * k0.y + q0.z * k0.z + q0.w * k0.w
                  + q1.x * k1.x + q1.y * k1.y + q1.z * k1.z + q1.w * k1.w;
        acc += __shfl_xor(acc, 1);
        acc += __shfl_xor(acc, 2);
        acc += __shfl_xor(acc, 4);
        vmax = fmaxf(vmax, acc);
        vsum += acc;
    }
    if (dg == 0) M[(size_t)(b * H + h) * L + l] = vmax - vsum / (float)S;
}

// ---------------------------------------------------------------- K2: top-40 radix select
__device__ inline unsigned int fkey(float f) {
    unsigned int u = __float_as_uint(f);
    return (u & 0x80000000u) ? ~u : (u | 0x80000000u);
}

__global__ void k_topk(const float* __restrict__ M, int* __restrict__ topidx) {
    int bh = blockIdx.x;
    const float* m = M + (size_t)bh * L;
    int tid = threadIdx.x;

    __shared__ int hist[256];
    __shared__ unsigned int prefix_s;
    __shared__ int c_above_s, nsel_s, ntie_s, r_s;
    __shared__ int tie_i[L];

    unsigned int o[8];
    const float4* mr = (const float4*)(m + tid * 8);
    float4 a0 = mr[0], a1 = mr[1];
    o[0] = fkey(a0.x); o[1] = fkey(a0.y); o[2] = fkey(a0.z); o[3] = fkey(a0.w);
    o[4] = fkey(a1.x); o[5] = fkey(a1.y); o[6] = fkey(a1.z); o[7] = fkey(a1.w);

    if (tid == 0) { prefix_s = 0u; c_above_s = 0; nsel_s = 0; ntie_s = 0; }

    for (int sh = 24; sh >= 0; sh -= 8) {
        hist[tid] = 0;
        __syncthreads();
        unsigned int pfx = prefix_s;
#pragma unroll
        for (int j = 0; j < 8; j++) {
            bool match = (sh == 24) || ((o[j] >> (sh + 8)) == (pfx >> (sh + 8)));
            if (match) atomicAdd(&hist[(o[j] >> sh) & 0xFF], 1);
        }
        __syncthreads();
        if (tid < 64) {
            int4 hv = *(const int4*)&hist[tid * 4];
            int lsum = hv.x + hv.y + hv.z + hv.w;
            int s = lsum;
#pragma unroll
            for (int off = 1; off < 64; off <<= 1) {
                int t = __shfl_down(s, off);
                if (tid + off < 64) s += t;
            }
            int tail = s - lsum;
            int acc = c_above_s;
            int need = NT - acc;
            int t3 = tail + hv.w;
            int t2 = t3 + hv.z;
            int t1 = t2 + hv.y;
            int t0 = t1 + hv.x;
            if (t0 >= need && t1 < need) { prefix_s |= (unsigned)(4 * tid + 0) << sh; c_above_s = acc + t1; }
            else if (t1 >= need && t2 < need) { prefix_s |= (unsigned)(4 * tid + 1) << sh; c_above_s = acc + t2; }
            else if (t2 >= need && t3 < need) { prefix_s |= (unsigned)(4 * tid + 2) << sh; c_above_s = acc + t3; }
            else if (t3 >= need && tail < need) { prefix_s |= (unsigned)(4 * tid + 3) << sh; c_above_s = acc + tail; }
        }
        __syncthreads();
    }

    unsigned int T = prefix_s;

#pragma unroll
    for (int j = 0; j < 8; j++) {
        if (o[j] > T) {
            int slot = atomicAdd(&nsel_s, 1);
            topidx[bh * NT + slot] = tid * 8 + j;
        } else if (o[j] == T) {
            int p = atomicAdd(&ntie_s, 1);
            tie_i[p] = tid * 8 + j;
        }
    }
    __syncthreads();
    if (tid == 0) r_s = NT - nsel_s;
    __syncthreads();
    int r = r_s, ntie = ntie_s;

#pragma unroll
    for (int j = 0; j < 8; j++) {
        if (o[j] == T) {
            int myidx = tid * 8 + j;
            int rank = 0;
            for (int p = 0; p < ntie; p++) rank += (tie_i[p] < myidx) ? 1 : 0;
            if (rank < r) {
                int slot = atomicAdd(&nsel_s, 1);
                topidx[bh * NT + slot] = myidx;
            }
        }
    }
}

// ---------------------------------------------------------------- K3: v mean (2-phase)
__global__ void k_meanv_part(const float* __restrict__ v, float* __restrict__ part) {
    int blk = blockIdx.x;
    int b = blk >> 5, c = blk & 31;
    int col = threadIdx.x;
    const float* p = v + ((size_t)(b * S + c * 64)) * 512 + col;
    float acc = 0.f;
#pragma unroll
    for (int s = 0; s < 64; s++) acc += p[(size_t)s * 512];
    part[(size_t)blk * 512 + col] = acc;
}

__global__ void k_meanv_final(const float* __restrict__ part, float* __restrict__ meanv) {
    int b = blockIdx.x; int col = threadIdx.x;
    float acc = 0.f;
#pragma unroll
    for (int c = 0; c < 32; c++) acc += part[(size_t)(b * 32 + c) * 512 + col];
    meanv[b * 512 + col] = acc * (1.f / (float)S);
}

// ---------------------------------------------------------------- K4: attention partials
// R7-proven structure (4 barriers = live-range fences, no spill) but each
// block handles only 20 of the 40 rows -> grid 512 = 2 blocks/CU, LDS 26 KB.
// Scores: wave = (row-group of 5) x (col-half of 128); lane owns 2 cols;
// scores stay in regs through exp. Stats: rows cyclic over waves. PV: wave g
// rows {g, g+8, g+16}, lane = d.
__global__ __launch_bounds__(512) void k_attn_part(
        const float* __restrict__ q, const float* __restrict__ k,
        const float* __restrict__ v, const int* __restrict__ topidx,
        float* __restrict__ pctx, float* __restrict__ pm, float* __restrict__ pl) {
    int blk = blockIdx.x;
    int bh = blk >> 4;
    int rem = blk & 15;
    int c = rem >> 1, half = rem & 1;
    int b = bh / H, h = bh % H;
    int s0 = c * CS;
    int n0 = half * RH;                  // global row offset of this block's rows
    int tid = threadIdx.x;
    int lane = tid & 63, g = tid >> 6;   // 8 waves

    __shared__ float q_s[RH][D];         // 5 KB
    __shared__ float p_s[RH][CS + 4];    // 20.8 KB
    __shared__ float m_c[RH];

    for (int i = tid; i < RH * D; i += 512) {
        int n = i >> 6, d = i & 63;
        int lsel = topidx[bh * NT + n0 + n];
        q_s[n][d] = q[((size_t)(b * L + lsel) * H + h) * D + d];
    }
    __syncthreads();

    // ---- scores: wave = (row-group rg of 5) x (col-half ch of 128)
    int rg = g & 3, ch = g >> 2;
    int r0 = rg * 5;
    int lc = (ch << 7) + (lane << 1);
    const float* kp0 = k + ((size_t)(b * S + s0 + lc) * H + h) * D;
    const float* kp1 = kp0 + H * D;

    float sc0[5], sc1[5];
#pragma unroll
    for (int j = 0; j < 5; j++) { sc0[j] = 0.f; sc1[j] = 0.f; }

#pragma unroll
    for (int dc = 0; dc < 64; dc += 16) {
        float4 ka0 = *(const float4*)(kp0 + dc);
        float4 ka1 = *(const float4*)(kp0 + dc + 4);
        float4 ka2 = *(const float4*)(kp0 + dc + 8);
        float4 ka3 = *(const float4*)(kp0 + dc + 12);
        float4 kb0 = *(const float4*)(kp1 + dc);
        float4 kb1 = *(const float4*)(kp1 + dc + 4);
        float4 kb2 = *(const float4*)(kp1 + dc + 8);
        float4 kb3 = *(const float4*)(kp1 + dc + 12);
#pragma unroll
        for (int j = 0; j < 5; j++) {
            const float4* qr = (const float4*)&q_s[r0 + j][dc];
            float4 q0 = qr[0], q1 = qr[1], q2 = qr[2], q3 = qr[3];
            sc0[j] += q0.x * ka0.x + q0.y * ka0.y + q0.z * ka0.z + q0.w * ka0.w
                    + q1.x * ka1.x + q1.y * ka1.y + q1.z * ka1.z + q1.w * ka1.w
                    + q2.x * ka2.x + q2.y * ka2.y + q2.z * ka2.z + q2.w * ka2.w
                    + q3.x * ka3.x + q3.y * ka3.y + q3.z * ka3.z + q3.w * ka3.w;
            sc1[j] += q0.x * kb0.x + q0.y * kb0.y + q0.z * kb0.z + q0.w * kb0.w
                    + q1.x * kb1.x + q1.y * kb1.y + q1.z * kb1.z + q1.w * kb1.w
                    + q2.x * kb2.x + q2.y * kb2.y + q2.z * kb2.z + q2.w * kb2.w
                    + q3.x * kb3.x + q3.y * kb3.y + q3.z * kb3.z + q3.w * kb3.w;
        }
    }
#pragma unroll
    for (int j = 0; j < 5; j++) {
        sc0[j] *= SCALE; sc1[j] *= SCALE;
        *(float2*)&p_s[r0 + j][lc] = make_float2(sc0[j], sc1[j]);
    }
    __syncthreads();

    // ---- row max: rows cyclic over waves; bank=(4n+lane)&31 -> 2-way, free
    for (int n = g; n < RH; n += 8) {
        float mx = fmaxf(fmaxf(p_s[n][lane], p_s[n][lane + 64]),
                         fmaxf(p_s[n][lane + 128], p_s[n][lane + 192]));
#pragma unroll
        for (int off = 1; off < 64; off <<= 1)
            mx = fmaxf(mx, __shfl_xor(mx, off));
        if (lane == 0) m_c[n] = mx;
    }
    __syncthreads();

    // ---- exp from registers
#pragma unroll
    for (int j = 0; j < 5; j++) {
        float mm = m_c[r0 + j];
        *(float2*)&p_s[r0 + j][lc] =
            make_float2(__expf(sc0[j] - mm), __expf(sc1[j] - mm));
    }
    __syncthreads();

    // ---- row sum + emit pm/pl
    for (int n = g; n < RH; n += 8) {
        float sum = p_s[n][lane] + p_s[n][lane + 64]
                  + p_s[n][lane + 128] + p_s[n][lane + 192];
#pragma unroll
        for (int off = 1; off < 64; off <<= 1) sum += __shfl_xor(sum, off);
        if (lane == 0) {
            pm[(bh * NCH + c) * NT + n0 + n] = m_c[n];
            pl[(bh * NCH + c) * NT + n0 + n] = sum;
        }
    }

    // ---- PV: wave g rows {g, g+8, g+16}, lane = d
    float acc[3];
    int nrows = (g < 4) ? 3 : 2;
#pragma unroll
    for (int r = 0; r < 3; r++) acc[r] = 0.f;
    const float* vb = v + ((size_t)(b * S + s0) * H + h) * D + lane;
    for (int t4 = 0; t4 < CS; t4 += 4) {
        float vd0 = vb[(size_t)(t4 + 0) * H * D];
        float vd1 = vb[(size_t)(t4 + 1) * H * D];
        float vd2 = vb[(size_t)(t4 + 2) * H * D];
        float vd3 = vb[(size_t)(t4 + 3) * H * D];
        for (int r = 0; r < nrows; r++) {
            float4 p4 = *(const float4*)&p_s[g + 8 * r][t4];
            acc[r] += p4.x * vd0 + p4.y * vd1 + p4.z * vd2 + p4.w * vd3;
        }
    }
    for (int r = 0; r < nrows; r++)
        pctx[((size_t)(bh * NCH + c) * NT + n0 + g + 8 * r) * D + lane] = acc[r];
}

// ---------------------------------------------------------------- K5: fill with mean
__global__ void k_fill(const float* __restrict__ meanv, float4* __restrict__ out) {
    int i = blockIdx.x * blockDim.x + threadIdx.x;
    int b = i >> 18;
    int col4 = i & 127;
    out[i] = ((const float4*)meanv)[(b << 7) | col4];
}

// ---------------------------------------------------------------- K6: combine + scatter
__global__ void k_combine(const int* __restrict__ topidx, const float* __restrict__ pctx,
                          const float* __restrict__ pm, const float* __restrict__ pl,
                          float* __restrict__ out) {
    int bh = blockIdx.x; int b = bh / H, h = bh % H;
    int tid = threadIdx.x;
    for (int i = tid; i < NT * D; i += 256) {
        int n = i / D, d = i % D;
        float mg = -INFINITY;
#pragma unroll
        for (int c = 0; c < NCH; c++) mg = fmaxf(mg, pm[(bh * NCH + c) * NT + n]);
        float lsum = 0.f, ctx = 0.f;
#pragma unroll
        for (int c = 0; c < NCH; c++) {
            float w = __expf(pm[(bh * NCH + c) * NT + n] - mg);
            lsum += pl[(bh * NCH + c) * NT + n] * w;
            ctx  += pctx[((size_t)(bh * NCH + c) * NT + n) * D + d] * w;
        }
        int lsel = topidx[bh * NT + n];
        out[((size_t)(b * L + lsel) * H + h) * D + d] = ctx / lsum;
    }
}

// ---------------------------------------------------------------- launch
extern "C" void kernel_launch(void* const* d_in, const int* in_sizes, int n_in,
                              void* d_out, int out_size, void* d_ws, size_t ws_size,
                              hipStream_t stream) {
    const float* q   = (const float*)d_in[0];
    const float* k   = (const float*)d_in[1];
    const float* v   = (const float*)d_in[2];
    const int*   idx = (const int*)d_in[3];
    float* out = (float*)d_out;

    float* ws = (float*)d_ws;
    float* M      = ws;                         // 65536 floats (reused as meanv partials)
    int*   topidx = (int*)(ws + 65536);         // 1280 ints
    float* meanv  = ws + 65536 + 1280;          // 2048
    float* pm     = meanv + 2048;               // 10240
    float* pl     = pm + 10240;                 // 10240
    float* pctx   = pl + 10240;                 // 655360

    k_compute_M<<<B * L / 4, 256, 0, stream>>>(q, k, idx, M);
    k_topk<<<B * H, 256, 0, stream>>>(M, topidx);
    k_meanv_part<<<B * 32, 512, 0, stream>>>(v, M);
    k_meanv_final<<<B, 512, 0, stream>>>(M, meanv);
    k_attn_part<<<B * H * NCH * 2, 512, 0, stream>>>(q, k, v, topidx, pctx, pm, pl);
    k_fill<<<(B * L * H * D / 4) / 256, 256, 0, stream>>>(meanv, (float4*)out);
    k_combine<<<B * H, 256, 0, stream>>>(topidx, pctx, pm, pl, out);
}

// Round 10
// 170.965 us; speedup vs baseline: 1.3566x; 1.1208x over previous
//
#include <hip/hip_runtime.h>
#include <math.h>

constexpr int B = 4, L = 2048, S = 2048, H = 8, D = 64;
constexpr int U  = 40;
constexpr int NT = 40;
constexpr float SCALE = 0.125f;

// ---------------------------------------------------------------- K1: M scores
__global__ void k_compute_M(const float* __restrict__ q, const float* __restrict__ k,
                            const int* __restrict__ idx, float* __restrict__ M) {
    int tid = threadIdx.x;
    int wid = tid >> 6, lane = tid & 63;
    int b = blockIdx.x & 3;
    int l = (blockIdx.x >> 2) * 4 + wid;
    int h = lane >> 3, dg = lane & 7;

    const float4* qr = (const float4*)(q + ((size_t)(b * L + l) * H + h) * D + dg * 8);
    float4 q0 = qr[0], q1 = qr[1];

    const int* irow = idx + l * U;
    const float* kb = k + (size_t)b * S * H * D + (size_t)h * D + dg * 8;
    float vmax = -INFINITY, vsum = 0.f;
#pragma unroll 4
    for (int u = 0; u < U; u++) {
        int s = irow[u];
        const float4* kr = (const float4*)(kb + (size_t)s * H * D);
        float4 k0 = kr[0], k1 = kr[1];
        float acc = q0.x * k0.x + q0.y * k0.y + q0.z * k0.z + q0.w * k0.w
                  + q1.x * k1.x + q1.y * k1.y + q1.z * k1.z + q1.w * k1.w;
        acc += __shfl_xor(acc, 1);
        acc += __shfl_xor(acc, 2);
        acc += __shfl_xor(acc, 4);
        vmax = fmaxf(vmax, acc);
        vsum += acc;
    }
    if (dg == 0) M[(size_t)(b * H + h) * L + l] = vmax - vsum / (float)S;
}

// ---------------------------------------------------------------- K2: top-40 radix select
__device__ inline unsigned int fkey(float f) {
    unsigned int u = __float_as_uint(f);
    return (u & 0x80000000u) ? ~u : (u | 0x80000000u);
}

__global__ void k_topk(const float* __restrict__ M, int* __restrict__ topidx) {
    int bh = blockIdx.x;
    const float* m = M + (size_t)bh * L;
    int tid = threadIdx.x;

    __shared__ int hist[256];
    __shared__ unsigned int prefix_s;
    __shared__ int c_above_s, nsel_s, ntie_s, r_s;
    __shared__ int tie_i[L];

    unsigned int o[8];
    const float4* mr = (const float4*)(m + tid * 8);
    float4 a0 = mr[0], a1 = mr[1];
    o[0] = fkey(a0.x); o[1] = fkey(a0.y); o[2] = fkey(a0.z); o[3] = fkey(a0.w);
    o[4] = fkey(a1.x); o[5] = fkey(a1.y); o[6] = fkey(a1.z); o[7] = fkey(a1.w);

    if (tid == 0) { prefix_s = 0u; c_above_s = 0; nsel_s = 0; ntie_s = 0; }

    for (int sh = 24; sh >= 0; sh -= 8) {
        hist[tid] = 0;
        __syncthreads();
        unsigned int pfx = prefix_s;
#pragma unroll
        for (int j = 0; j < 8; j++) {
            bool match = (sh == 24) || ((o[j] >> (sh + 8)) == (pfx >> (sh + 8)));
            if (match) atomicAdd(&hist[(o[j] >> sh) & 0xFF], 1);
        }
        __syncthreads();
        if (tid < 64) {
            int4 hv = *(const int4*)&hist[tid * 4];
            int lsum = hv.x + hv.y + hv.z + hv.w;
            int s = lsum;
#pragma unroll
            for (int off = 1; off < 64; off <<= 1) {
                int t = __shfl_down(s, off);
                if (tid + off < 64) s += t;
            }
            int tail = s - lsum;
            int acc = c_above_s;
            int need = NT - acc;
            int t3 = tail + hv.w;
            int t2 = t3 + hv.z;
            int t1 = t2 + hv.y;
            int t0 = t1 + hv.x;
            if (t0 >= need && t1 < need) { prefix_s |= (unsigned)(4 * tid + 0) << sh; c_above_s = acc + t1; }
            else if (t1 >= need && t2 < need) { prefix_s |= (unsigned)(4 * tid + 1) << sh; c_above_s = acc + t2; }
            else if (t2 >= need && t3 < need) { prefix_s |= (unsigned)(4 * tid + 2) << sh; c_above_s = acc + t3; }
            else if (t3 >= need && tail < need) { prefix_s |= (unsigned)(4 * tid + 3) << sh; c_above_s = acc + tail; }
        }
        __syncthreads();
    }

    unsigned int T = prefix_s;

#pragma unroll
    for (int j = 0; j < 8; j++) {
        if (o[j] > T) {
            int slot = atomicAdd(&nsel_s, 1);
            topidx[bh * NT + slot] = tid * 8 + j;
        } else if (o[j] == T) {
            int p = atomicAdd(&ntie_s, 1);
            tie_i[p] = tid * 8 + j;
        }
    }
    __syncthreads();
    if (tid == 0) r_s = NT - nsel_s;
    __syncthreads();
    int r = r_s, ntie = ntie_s;

#pragma unroll
    for (int j = 0; j < 8; j++) {
        if (o[j] == T) {
            int myidx = tid * 8 + j;
            int rank = 0;
            for (int p = 0; p < ntie; p++) rank += (tie_i[p] < myidx) ? 1 : 0;
            if (rank < r) {
                int slot = atomicAdd(&nsel_s, 1);
                topidx[bh * NT + slot] = myidx;
            }
        }
    }
}

// ---------------------------------------------------------------- K3: v mean (2-phase)
__global__ void k_meanv_part(const float* __restrict__ v, float* __restrict__ part) {
    int blk = blockIdx.x;
    int b = blk >> 5, c = blk & 31;
    int col = threadIdx.x;
    const float* p = v + ((size_t)(b * S + c * 64)) * 512 + col;
    float acc = 0.f;
#pragma unroll
    for (int s = 0; s < 64; s++) acc += p[(size_t)s * 512];
    part[(size_t)blk * 512 + col] = acc;
}

__global__ void k_meanv_final(const float* __restrict__ part, float* __restrict__ meanv) {
    int b = blockIdx.x; int col = threadIdx.x;
    float acc = 0.f;
#pragma unroll
    for (int c = 0; c < 32; c++) acc += part[(size_t)(b * 32 + c) * 512 + col];
    meanv[b * 512 + col] = acc * (1.f / (float)S);
}

// ---------------------------------------------------------------- K4: attention partials
// R7-proven 4-barrier skeleton (barriers double as live-range fences -> no
// spill). Split along COLUMNS: NCH_ chunks partition S, so K/V traffic is not
// duplicated. 512 thr = 8 waves = 4 row-groups (10 rows) x 2 col-halves; lane
// owns CPL columns (CPL = CS_/128). Scores stay in regs through exp. Stats:
// rows cyclic over waves with butterfly. PV: wave g owns rows 5g..5g+4.
template <int NCH_>
__global__ __launch_bounds__(512) void k_attn_part(
        const float* __restrict__ q, const float* __restrict__ k,
        const float* __restrict__ v, const int* __restrict__ topidx,
        float* __restrict__ pctx, float* __restrict__ pm, float* __restrict__ pl) {
    constexpr int CS_ = S / NCH_;        // 128 (or 256 fallback)
    constexpr int CPL = CS_ / 128;       // 1 (or 2)
    int blk = blockIdx.x;
    int bh = blk / NCH_, c = blk % NCH_;
    int b = bh / H, h = bh % H;
    int s0 = c * CS_;
    int tid = threadIdx.x;
    int lane = tid & 63, g = tid >> 6;   // 8 waves

    __shared__ float q_s[NT][D];         // 10 KB
    __shared__ float p_s[NT][CS_ + 4];   // 21.1 KB @ CS=128
    __shared__ float m_c[NT];

    for (int i = tid; i < NT * D; i += 512) {
        int n = i >> 6, d = i & 63;
        int lsel = topidx[bh * NT + n];
        q_s[n][d] = q[((size_t)(b * L + lsel) * H + h) * D + d];
    }
    __syncthreads();

    // ---- scores: wave = (row-group rg of 10) x (col-half ch of CS_/2)
    int rg = g & 3, ch = g >> 2;
    int r0 = rg * 10;
    int lc = ch * (CS_ / 2) + lane * CPL;
    const float* kp = k + ((size_t)(b * S + s0 + lc) * H + h) * D;

    float sc[10][CPL];
#pragma unroll
    for (int j = 0; j < 10; j++)
#pragma unroll
        for (int p = 0; p < CPL; p++) sc[j][p] = 0.f;

#pragma unroll
    for (int dc = 0; dc < 64; dc += 16) {
        float4 kf[CPL][4];
#pragma unroll
        for (int p = 0; p < CPL; p++) {
            const float* kc = kp + (size_t)p * H * D + dc;
            kf[p][0] = *(const float4*)(kc);
            kf[p][1] = *(const float4*)(kc + 4);
            kf[p][2] = *(const float4*)(kc + 8);
            kf[p][3] = *(const float4*)(kc + 12);
        }
#pragma unroll
        for (int j = 0; j < 10; j++) {
            const float4* qr = (const float4*)&q_s[r0 + j][dc];
            float4 q0 = qr[0], q1 = qr[1], q2 = qr[2], q3 = qr[3];
#pragma unroll
            for (int p = 0; p < CPL; p++) {
                sc[j][p] += q0.x * kf[p][0].x + q0.y * kf[p][0].y + q0.z * kf[p][0].z + q0.w * kf[p][0].w
                          + q1.x * kf[p][1].x + q1.y * kf[p][1].y + q1.z * kf[p][1].z + q1.w * kf[p][1].w
                          + q2.x * kf[p][2].x + q2.y * kf[p][2].y + q2.z * kf[p][2].z + q2.w * kf[p][2].w
                          + q3.x * kf[p][3].x + q3.y * kf[p][3].y + q3.z * kf[p][3].z + q3.w * kf[p][3].w;
            }
        }
    }
#pragma unroll
    for (int j = 0; j < 10; j++) {
#pragma unroll
        for (int p = 0; p < CPL; p++) sc[j][p] *= SCALE;
        if (CPL == 1) p_s[r0 + j][lc] = sc[j][0];
        else *(float2*)&p_s[r0 + j][lc] = make_float2(sc[j][0], sc[j][1]);
    }
    __syncthreads();

    // ---- row max: rows cyclic over waves
    for (int n = g; n < NT; n += 8) {
        float mx = -INFINITY;
#pragma unroll
        for (int jj = 0; jj < CS_ / 64; jj++) mx = fmaxf(mx, p_s[n][lane + 64 * jj]);
#pragma unroll
        for (int off = 1; off < 64; off <<= 1)
            mx = fmaxf(mx, __shfl_xor(mx, off));
        if (lane == 0) m_c[n] = mx;
    }
    __syncthreads();

    // ---- exp from registers
#pragma unroll
    for (int j = 0; j < 10; j++) {
        float mm = m_c[r0 + j];
        if (CPL == 1) p_s[r0 + j][lc] = __expf(sc[j][0] - mm);
        else *(float2*)&p_s[r0 + j][lc] =
                 make_float2(__expf(sc[j][0] - mm), __expf(sc[j][1] - mm));
    }
    __syncthreads();

    // ---- row sum + emit pm/pl
    for (int n = g; n < NT; n += 8) {
        float sum = 0.f;
#pragma unroll
        for (int jj = 0; jj < CS_ / 64; jj++) sum += p_s[n][lane + 64 * jj];
#pragma unroll
        for (int off = 1; off < 64; off <<= 1) sum += __shfl_xor(sum, off);
        if (lane == 0) {
            pm[(bh * NCH_ + c) * NT + n] = m_c[n];
            pl[(bh * NCH_ + c) * NT + n] = sum;
        }
    }

    // ---- PV: wave g rows 5g..5g+4, lane = d
    float acc[5];
#pragma unroll
    for (int r = 0; r < 5; r++) acc[r] = 0.f;
    int rp = g * 5;
    const float* vb = v + ((size_t)(b * S + s0) * H + h) * D + lane;
    for (int t4 = 0; t4 < CS_; t4 += 4) {
        float vd0 = vb[(size_t)(t4 + 0) * H * D];
        float vd1 = vb[(size_t)(t4 + 1) * H * D];
        float vd2 = vb[(size_t)(t4 + 2) * H * D];
        float vd3 = vb[(size_t)(t4 + 3) * H * D];
#pragma unroll
        for (int r = 0; r < 5; r++) {
            float4 p4 = *(const float4*)&p_s[rp + r][t4];
            acc[r] += p4.x * vd0 + p4.y * vd1 + p4.z * vd2 + p4.w * vd3;
        }
    }
#pragma unroll
    for (int r = 0; r < 5; r++)
        pctx[((size_t)(bh * NCH_ + c) * NT + rp + r) * D + lane] = acc[r];
}

// ---------------------------------------------------------------- K5: fill with mean
__global__ void k_fill(const float* __restrict__ meanv, float4* __restrict__ out) {
    int i = blockIdx.x * blockDim.x + threadIdx.x;
    int b = i >> 18;
    int col4 = i & 127;
    out[i] = ((const float4*)meanv)[(b << 7) | col4];
}

// ---------------------------------------------------------------- K6: combine + scatter
template <int NCH_>
__global__ void k_combine(const int* __restrict__ topidx, const float* __restrict__ pctx,
                          const float* __restrict__ pm, const float* __restrict__ pl,
                          float* __restrict__ out) {
    int bh = blockIdx.x; int b = bh / H, h = bh % H;
    int tid = threadIdx.x;
    for (int i = tid; i < NT * D; i += 256) {
        int n = i / D, d = i % D;
        float mg = -INFINITY;
#pragma unroll
        for (int c = 0; c < NCH_; c++) mg = fmaxf(mg, pm[(bh * NCH_ + c) * NT + n]);
        float lsum = 0.f, ctx = 0.f;
#pragma unroll
        for (int c = 0; c < NCH_; c++) {
            float w = __expf(pm[(bh * NCH_ + c) * NT + n] - mg);
            lsum += pl[(bh * NCH_ + c) * NT + n] * w;
            ctx  += pctx[((size_t)(bh * NCH_ + c) * NT + n) * D + d] * w;
        }
        int lsel = topidx[bh * NT + n];
        out[((size_t)(b * L + lsel) * H + h) * D + d] = ctx / lsum;
    }
}

// ---------------------------------------------------------------- launch
extern "C" void kernel_launch(void* const* d_in, const int* in_sizes, int n_in,
                              void* d_out, int out_size, void* d_ws, size_t ws_size,
                              hipStream_t stream) {
    const float* q   = (const float*)d_in[0];
    const float* k   = (const float*)d_in[1];
    const float* v   = (const float*)d_in[2];
    const int*   idx = (const int*)d_in[3];
    float* out = (float*)d_out;

    float* ws = (float*)d_ws;
    float* M      = ws;                         // 65536 floats (reused as meanv partials)
    int*   topidx = (int*)(ws + 65536);         // 1280 ints
    float* meanv  = ws + 65536 + 1280;          // 2048
    float* pm     = meanv + 2048;               // B*H*NCH*NT

    k_compute_M<<<B * L / 4, 256, 0, stream>>>(q, k, idx, M);
    k_topk<<<B * H, 256, 0, stream>>>(M, topidx);
    k_meanv_part<<<B * 32, 512, 0, stream>>>(v, M);
    k_meanv_final<<<B, 512, 0, stream>>>(M, meanv);

    constexpr size_t base_floats = 65536 + 1280 + 2048;
    constexpr size_t need16 = (base_floats + 2ull * (32 * 16 * 40) + 32ull * 16 * 40 * 64) * 4;
    if (ws_size >= need16) {
        constexpr int NCH_ = 16;
        float* pl   = pm + 32 * NCH_ * NT;
        float* pctx = pl + 32 * NCH_ * NT;
        k_attn_part<NCH_><<<B * H * NCH_, 512, 0, stream>>>(q, k, v, topidx, pctx, pm, pl);
        k_fill<<<(B * L * H * D / 4) / 256, 256, 0, stream>>>(meanv, (float4*)out);
        k_combine<NCH_><<<B * H, 256, 0, stream>>>(topidx, pctx, pm, pl, out);
    } else {
        constexpr int NCH_ = 8;
        float* pl   = pm + 32 * NCH_ * NT;
        float* pctx = pl + 32 * NCH_ * NT;
        k_attn_part<NCH_><<<B * H * NCH_, 512, 0, stream>>>(q, k, v, topidx, pctx, pm, pl);
        k_fill<<<(B * L * H * D / 4) / 256, 256, 0, stream>>>(meanv, (float4*)out);
        k_combine<NCH_><<<B * H, 256, 0, stream>>>(topidx, pctx, pm, pl, out);
    }
}

// Round 11
// 162.040 us; speedup vs baseline: 1.4313x; 1.0551x over previous
//
#include <hip/hip_runtime.h>
#include <math.h>

constexpr int B = 4, L = 2048, S = 2048, H = 8, D = 64;
constexpr int U  = 40;
constexpr int NT = 40;
constexpr float SCALE = 0.125f;

// ---------------------------------------------------------------- K1: M scores + v-mean partials
// Blocks [0,2048): one wave per (b,l), lane = h*8+dg, 3-shuffle dot reduce.
// Blocks [2048,2176): v column partial sums (64 s-rows per block).
__global__ void k_M_meanvpart(const float* __restrict__ q, const float* __restrict__ k,
                              const float* __restrict__ v, const int* __restrict__ idx,
                              float* __restrict__ M, float* __restrict__ part) {
    int tid = threadIdx.x;
    if (blockIdx.x < 2048) {
        int wid = tid >> 6, lane = tid & 63;
        int b = blockIdx.x & 3;
        int l = (blockIdx.x >> 2) * 4 + wid;
        int h = lane >> 3, dg = lane & 7;

        const float4* qr = (const float4*)(q + ((size_t)(b * L + l) * H + h) * D + dg * 8);
        float4 q0 = qr[0], q1 = qr[1];

        const int* irow = idx + l * U;
        const float* kb = k + (size_t)b * S * H * D + (size_t)h * D + dg * 8;
        float vmax = -INFINITY, vsum = 0.f;
#pragma unroll 4
        for (int u = 0; u < U; u++) {
            int s = irow[u];
            const float4* kr = (const float4*)(kb + (size_t)s * H * D);
            float4 k0 = kr[0], k1 = kr[1];
            float acc = q0.x * k0.x + q0.y * k0.y + q0.z * k0.z + q0.w * k0.w
                      + q1.x * k1.x + q1.y * k1.y + q1.z * k1.z + q1.w * k1.w;
            acc += __shfl_xor(acc, 1);
            acc += __shfl_xor(acc, 2);
            acc += __shfl_xor(acc, 4);
            vmax = fmaxf(vmax, acc);
            vsum += acc;
        }
        if (dg == 0) M[(size_t)(b * H + h) * L + l] = vmax - vsum / (float)S;
    } else {
        int blk = blockIdx.x - 2048;         // 0..127 = b*32 + c
        int b = blk >> 5, c = blk & 31;
        const float* p = v + ((size_t)(b * S + c * 64)) * 512;
        float a0 = 0.f, a1 = 0.f;
#pragma unroll
        for (int s = 0; s < 64; s++) {
            a0 += p[(size_t)s * 512 + tid];
            a1 += p[(size_t)s * 512 + tid + 256];
        }
        part[(size_t)blk * 512 + tid]       = a0;
        part[(size_t)blk * 512 + tid + 256] = a1;
    }
}

// ---------------------------------------------------------------- K2: top-40 radix select + v-mean final
__device__ inline unsigned int fkey(float f) {
    unsigned int u = __float_as_uint(f);
    return (u & 0x80000000u) ? ~u : (u | 0x80000000u);
}

__global__ void k_topk_meanv(const float* __restrict__ M, int* __restrict__ topidx,
                             const float* __restrict__ part, float* __restrict__ meanv) {
    int tid = threadIdx.x;
    if (blockIdx.x >= 32) {
        int b = blockIdx.x - 32;             // 0..3
        float a0 = 0.f, a1 = 0.f;
#pragma unroll
        for (int c = 0; c < 32; c++) {
            a0 += part[(size_t)(b * 32 + c) * 512 + tid];
            a1 += part[(size_t)(b * 32 + c) * 512 + tid + 256];
        }
        meanv[b * 512 + tid]       = a0 * (1.f / (float)S);
        meanv[b * 512 + tid + 256] = a1 * (1.f / (float)S);
        return;
    }
    int bh = blockIdx.x;
    const float* m = M + (size_t)bh * L;

    __shared__ int hist[256];
    __shared__ unsigned int prefix_s;
    __shared__ int c_above_s, nsel_s, ntie_s, r_s;
    __shared__ int tie_i[L];

    unsigned int o[8];
    const float4* mr = (const float4*)(m + tid * 8);
    float4 a0 = mr[0], a1 = mr[1];
    o[0] = fkey(a0.x); o[1] = fkey(a0.y); o[2] = fkey(a0.z); o[3] = fkey(a0.w);
    o[4] = fkey(a1.x); o[5] = fkey(a1.y); o[6] = fkey(a1.z); o[7] = fkey(a1.w);

    if (tid == 0) { prefix_s = 0u; c_above_s = 0; nsel_s = 0; ntie_s = 0; }

    for (int sh = 24; sh >= 0; sh -= 8) {
        hist[tid] = 0;
        __syncthreads();
        unsigned int pfx = prefix_s;
#pragma unroll
        for (int j = 0; j < 8; j++) {
            bool match = (sh == 24) || ((o[j] >> (sh + 8)) == (pfx >> (sh + 8)));
            if (match) atomicAdd(&hist[(o[j] >> sh) & 0xFF], 1);
        }
        __syncthreads();
        if (tid < 64) {
            int4 hv = *(const int4*)&hist[tid * 4];
            int lsum = hv.x + hv.y + hv.z + hv.w;
            int s = lsum;
#pragma unroll
            for (int off = 1; off < 64; off <<= 1) {
                int t = __shfl_down(s, off);
                if (tid + off < 64) s += t;
            }
            int tail = s - lsum;
            int acc = c_above_s;
            int need = NT - acc;
            int t3 = tail + hv.w;
            int t2 = t3 + hv.z;
            int t1 = t2 + hv.y;
            int t0 = t1 + hv.x;
            if (t0 >= need && t1 < need) { prefix_s |= (unsigned)(4 * tid + 0) << sh; c_above_s = acc + t1; }
            else if (t1 >= need && t2 < need) { prefix_s |= (unsigned)(4 * tid + 1) << sh; c_above_s = acc + t2; }
            else if (t2 >= need && t3 < need) { prefix_s |= (unsigned)(4 * tid + 2) << sh; c_above_s = acc + t3; }
            else if (t3 >= need && tail < need) { prefix_s |= (unsigned)(4 * tid + 3) << sh; c_above_s = acc + tail; }
        }
        __syncthreads();
    }

    unsigned int T = prefix_s;

#pragma unroll
    for (int j = 0; j < 8; j++) {
        if (o[j] > T) {
            int slot = atomicAdd(&nsel_s, 1);
            topidx[bh * NT + slot] = tid * 8 + j;
        } else if (o[j] == T) {
            int p = atomicAdd(&ntie_s, 1);
            tie_i[p] = tid * 8 + j;
        }
    }
    __syncthreads();
    if (tid == 0) r_s = NT - nsel_s;
    __syncthreads();
    int r = r_s, ntie = ntie_s;

#pragma unroll
    for (int j = 0; j < 8; j++) {
        if (o[j] == T) {
            int myidx = tid * 8 + j;
            int rank = 0;
            for (int p = 0; p < ntie; p++) rank += (tie_i[p] < myidx) ? 1 : 0;
            if (rank < r) {
                int slot = atomicAdd(&nsel_s, 1);
                topidx[bh * NT + slot] = myidx;
            }
        }
    }
}

// ---------------------------------------------------------------- K3: attention partials + mean-fill
// R10 column-split structure (NCH_ chunks partition S; 4-barrier skeleton, no
// spill) with the broadcast-mean fill of `out` appended per block (independent
// of attn LDS/phases; no extra barrier).
template <int NCH_>
__global__ __launch_bounds__(512) void k_attn_fill(
        const float* __restrict__ q, const float* __restrict__ k,
        const float* __restrict__ v, const int* __restrict__ topidx,
        const float* __restrict__ meanv,
        float* __restrict__ pctx, float* __restrict__ pm, float* __restrict__ pl,
        float4* __restrict__ out4) {
    constexpr int CS_ = S / NCH_;        // 128 @ NCH16
    constexpr int CPL = CS_ / 128;       // 1 @ NCH16
    int blk = blockIdx.x;
    int bh = blk / NCH_, c = blk % NCH_;
    int b = bh / H, h = bh % H;
    int s0 = c * CS_;
    int tid = threadIdx.x;
    int lane = tid & 63, g = tid >> 6;   // 8 waves

    __shared__ float q_s[NT][D];
    __shared__ float p_s[NT][CS_ + 4];
    __shared__ float m_c[NT];

    for (int i = tid; i < NT * D; i += 512) {
        int n = i >> 6, d = i & 63;
        int lsel = topidx[bh * NT + n];
        q_s[n][d] = q[((size_t)(b * L + lsel) * H + h) * D + d];
    }
    __syncthreads();

    int rg = g & 3, ch = g >> 2;
    int r0 = rg * 10;
    int lc = ch * (CS_ / 2) + lane * CPL;
    const float* kp = k + ((size_t)(b * S + s0 + lc) * H + h) * D;

    float sc[10][CPL];
#pragma unroll
    for (int j = 0; j < 10; j++)
#pragma unroll
        for (int p = 0; p < CPL; p++) sc[j][p] = 0.f;

#pragma unroll
    for (int dc = 0; dc < 64; dc += 16) {
        float4 kf[CPL][4];
#pragma unroll
        for (int p = 0; p < CPL; p++) {
            const float* kc = kp + (size_t)p * H * D + dc;
            kf[p][0] = *(const float4*)(kc);
            kf[p][1] = *(const float4*)(kc + 4);
            kf[p][2] = *(const float4*)(kc + 8);
            kf[p][3] = *(const float4*)(kc + 12);
        }
#pragma unroll
        for (int j = 0; j < 10; j++) {
            const float4* qr = (const float4*)&q_s[r0 + j][dc];
            float4 q0 = qr[0], q1 = qr[1], q2 = qr[2], q3 = qr[3];
#pragma unroll
            for (int p = 0; p < CPL; p++) {
                sc[j][p] += q0.x * kf[p][0].x + q0.y * kf[p][0].y + q0.z * kf[p][0].z + q0.w * kf[p][0].w
                          + q1.x * kf[p][1].x + q1.y * kf[p][1].y + q1.z * kf[p][1].z + q1.w * kf[p][1].w
                          + q2.x * kf[p][2].x + q2.y * kf[p][2].y + q2.z * kf[p][2].z + q2.w * kf[p][2].w
                          + q3.x * kf[p][3].x + q3.y * kf[p][3].y + q3.z * kf[p][3].z + q3.w * kf[p][3].w;
            }
        }
    }
#pragma unroll
    for (int j = 0; j < 10; j++) {
#pragma unroll
        for (int p = 0; p < CPL; p++) sc[j][p] *= SCALE;
        if (CPL == 1) p_s[r0 + j][lc] = sc[j][0];
        else *(float2*)&p_s[r0 + j][lc] = make_float2(sc[j][0], sc[j][1]);
    }
    __syncthreads();

    for (int n = g; n < NT; n += 8) {
        float mx = -INFINITY;
#pragma unroll
        for (int jj = 0; jj < CS_ / 64; jj++) mx = fmaxf(mx, p_s[n][lane + 64 * jj]);
#pragma unroll
        for (int off = 1; off < 64; off <<= 1)
            mx = fmaxf(mx, __shfl_xor(mx, off));
        if (lane == 0) m_c[n] = mx;
    }
    __syncthreads();

#pragma unroll
    for (int j = 0; j < 10; j++) {
        float mm = m_c[r0 + j];
        if (CPL == 1) p_s[r0 + j][lc] = __expf(sc[j][0] - mm);
        else *(float2*)&p_s[r0 + j][lc] =
                 make_float2(__expf(sc[j][0] - mm), __expf(sc[j][1] - mm));
    }
    __syncthreads();

    for (int n = g; n < NT; n += 8) {
        float sum = 0.f;
#pragma unroll
        for (int jj = 0; jj < CS_ / 64; jj++) sum += p_s[n][lane + 64 * jj];
#pragma unroll
        for (int off = 1; off < 64; off <<= 1) sum += __shfl_xor(sum, off);
        if (lane == 0) {
            pm[(bh * NCH_ + c) * NT + n] = m_c[n];
            pl[(bh * NCH_ + c) * NT + n] = sum;
        }
    }

    float acc[5];
#pragma unroll
    for (int r = 0; r < 5; r++) acc[r] = 0.f;
    int rp = g * 5;
    const float* vb = v + ((size_t)(b * S + s0) * H + h) * D + lane;
    for (int t4 = 0; t4 < CS_; t4 += 4) {
        float vd0 = vb[(size_t)(t4 + 0) * H * D];
        float vd1 = vb[(size_t)(t4 + 1) * H * D];
        float vd2 = vb[(size_t)(t4 + 2) * H * D];
        float vd3 = vb[(size_t)(t4 + 3) * H * D];
#pragma unroll
        for (int r = 0; r < 5; r++) {
            float4 p4 = *(const float4*)&p_s[rp + r][t4];
            acc[r] += p4.x * vd0 + p4.y * vd1 + p4.z * vd2 + p4.w * vd3;
        }
    }
#pragma unroll
    for (int r = 0; r < 5; r++)
        pctx[((size_t)(bh * NCH_ + c) * NT + rp + r) * D + lane] = acc[r];

    // ---- mean-fill slice of out (independent of attn phases above)
    constexpr int FPB = 1048576 / (32 * NCH_);       // float4s per block (2048 @ NCH16)
    const float4* mv4 = (const float4*)meanv;
    size_t base = (size_t)blk * FPB;
#pragma unroll
    for (int j = 0; j < FPB / 512; j++) {
        size_t i = base + tid + (size_t)j * 512;
        int bb = (int)(i >> 18);
        int col4 = (int)(i & 127);
        out4[i] = mv4[(bb << 7) | col4];
    }
}

// ---------------------------------------------------------------- K4: combine + scatter
template <int NCH_>
__global__ void k_combine(const int* __restrict__ topidx, const float* __restrict__ pctx,
                          const float* __restrict__ pm, const float* __restrict__ pl,
                          float* __restrict__ out) {
    int bh = blockIdx.x; int b = bh / H, h = bh % H;
    int tid = threadIdx.x;
    for (int i = tid; i < NT * D; i += 256) {
        int n = i / D, d = i % D;
        float mg = -INFINITY;
#pragma unroll
        for (int c = 0; c < NCH_; c++) mg = fmaxf(mg, pm[(bh * NCH_ + c) * NT + n]);
        float lsum = 0.f, ctx = 0.f;
#pragma unroll
        for (int c = 0; c < NCH_; c++) {
            float w = __expf(pm[(bh * NCH_ + c) * NT + n] - mg);
            lsum += pl[(bh * NCH_ + c) * NT + n] * w;
            ctx  += pctx[((size_t)(bh * NCH_ + c) * NT + n) * D + d] * w;
        }
        int lsel = topidx[bh * NT + n];
        out[((size_t)(b * L + lsel) * H + h) * D + d] = ctx / lsum;
    }
}

// ---------------------------------------------------------------- launch
extern "C" void kernel_launch(void* const* d_in, const int* in_sizes, int n_in,
                              void* d_out, int out_size, void* d_ws, size_t ws_size,
                              hipStream_t stream) {
    const float* q   = (const float*)d_in[0];
    const float* k   = (const float*)d_in[1];
    const float* v   = (const float*)d_in[2];
    const int*   idx = (const int*)d_in[3];
    float* out = (float*)d_out;

    float* ws = (float*)d_ws;
    float* M      = ws;                         // 65536 floats
    int*   topidx = (int*)(ws + 65536);         // 1280 ints
    float* meanv  = ws + 65536 + 1280;          // 2048
    float* part   = meanv + 2048;               // 128*512 = 65536
    float* pm     = part + 65536;               // B*H*NCH*NT

    k_M_meanvpart<<<2048 + 128, 256, 0, stream>>>(q, k, v, idx, M, part);
    k_topk_meanv<<<36, 256, 0, stream>>>(M, topidx, part, meanv);

    constexpr size_t base_floats = 65536 + 1280 + 2048 + 65536;
    constexpr size_t need16 = (base_floats + 2ull * (32 * 16 * 40) + 32ull * 16 * 40 * 64) * 4;
    if (ws_size >= need16) {
        constexpr int NCH_ = 16;
        float* pl   = pm + 32 * NCH_ * NT;
        float* pctx = pl + 32 * NCH_ * NT;
        k_attn_fill<NCH_><<<B * H * NCH_, 512, 0, stream>>>(q, k, v, topidx, meanv,
                                                            pctx, pm, pl, (float4*)out);
        k_combine<NCH_><<<B * H, 256, 0, stream>>>(topidx, pctx, pm, pl, out);
    } else {
        constexpr int NCH_ = 8;
        float* pl   = pm + 32 * NCH_ * NT;
        float* pctx = pl + 32 * NCH_ * NT;
        k_attn_fill<NCH_><<<B * H * NCH_, 512, 0, stream>>>(q, k, v, topidx, meanv,
                                                            pctx, pm, pl, (float4*)out);
        k_combine<NCH_><<<B * H, 256, 0, stream>>>(topidx, pctx, pm, pl, out);
    }
}